// Round 4
// baseline (225.647 us; speedup 1.0000x reference)
//
#include <hip/hip_runtime.h>

#define BATCH 32
#define NFREQ 128
#define NTIME 8192
#define NROWS (BATCH * NFREQ)   // 4096 (b,i) output rows

// ---------------------------------------------------------------------------
// Single fused kernel. One block per output row (b,i):
//
//   gather:  threads 0..127 load  v0[y] = S[b, y, x0(i)]
//            threads 128..255 load v1[y] = S[b, y, x1(i)]   (parallel, 2x MLP
//            vs the old fallback where 128 threads each did both loads)
//   blend:   m[y] = v0 + wx*(v1 - v0)        (x-direction lerp, done once)
//   stream:  out[b,i,j] = lerp_y(m)          (coalesced float4 stores, 32 KB)
//
// vs the two-phase version this removes: one kernel launch, the 2 MB W
// write + read round-trip, and the graph-serialized dependency between the
// two dispatches. Gather latency (~0.5 us of scattered HBM reads per block)
// hides across the 8-16 resident blocks/CU while other blocks stream stores.
// ---------------------------------------------------------------------------
__global__ __launch_bounds__(256) void timewarp_fused_kernel(
    const float* __restrict__ S,
    const int* __restrict__ src_p,
    const int* __restrict__ dst_p,
    float* __restrict__ out)
{
    const float sourcef = (float)src_p[0];
    const float destf   = (float)dst_p[0];
    const float Tm1 = (float)(NTIME - 1);
    const float Fm1 = (float)(NFREQ - 1);
    const float inv_left  = sourcef / destf;                                   // 1/left_ratio
    const float inv_right = ((float)NTIME - sourcef) / ((float)NTIME - destf); // 1/right_ratio
    const float y_scale   = Fm1 / Tm1;

    const int row = blockIdx.x;          // b*NFREQ + i
    const int i   = row & (NFREQ - 1);
    const int b   = row >> 7;

    // x_pix = i/(F-1)*(T-1), border clamp (no-op for valid i, kept faithful)
    float x_pix = ((float)i / Fm1) * Tm1;
    x_pix = fminf(fmaxf(x_pix, 0.0f), Tm1);
    const int   x0 = (int)floorf(x_pix);
    const int   x1 = min(x0 + 1, NTIME - 1);
    const float wx = x_pix - (float)x0;

    const float* Sb = S + (size_t)b * (NFREQ * NTIME);

    __shared__ float v0s[NFREQ];
    __shared__ float v1s[NFREQ];
    __shared__ float m[NFREQ];

    const int t = threadIdx.x;
    if (t < NFREQ) {
        v0s[t] = Sb[(size_t)t * NTIME + x0];
    } else {
        v1s[t - NFREQ] = Sb[(size_t)(t - NFREQ) * NTIME + x1];
    }
    __syncthreads();
    if (t < NFREQ) {
        const float v0 = v0s[t];
        m[t] = v0 + wx * (v1s[t] - v0);
    }
    __syncthreads();

    float* orow = out + (size_t)row * NTIME;

#pragma unroll
    for (int c = 0; c < 8; ++c) {
        const int f = c * 256 + threadIdx.x;   // float4 index within the row
        const int j0 = f * 4;
        float4 r;
        float* rp = &r.x;
#pragma unroll
        for (int k = 0; k < 4; ++k) {
            const float t2 = (float)(j0 + k);
            float idx = (t2 < destf) ? (t2 * inv_left)
                                     : fmaf(t2 - destf, inv_right, sourcef);
            idx = fminf(fmaxf(idx, 0.0f), Tm1);          // clip to [0, T-1]
            float y_pix = idx * y_scale;
            y_pix = fminf(fmaxf(y_pix, 0.0f), Fm1);      // border clamp
            const float y0f = floorf(y_pix);
            const int   y0  = (int)y0f;
            const int   y1  = min(y0 + 1, NFREQ - 1);
            const float wy  = y_pix - y0f;
            const float m0  = m[y0];
            rp[k] = m0 + wy * (m[y1] - m0);
        }
        ((float4*)orow)[f] = r;                          // coalesced 16B store
    }
}

extern "C" void kernel_launch(void* const* d_in, const int* in_sizes, int n_in,
                              void* d_out, int out_size, void* d_ws, size_t ws_size,
                              hipStream_t stream) {
    const float* S   = (const float*)d_in[0];
    const int*   sp  = (const int*)d_in[1];
    const int*   dp  = (const int*)d_in[2];
    float*       out = (float*)d_out;

    (void)d_ws; (void)ws_size;

    // Single fused dispatch: one block per (b,i) output row.
    timewarp_fused_kernel<<<dim3(NROWS), dim3(256), 0, stream>>>(S, sp, dp, out);
}